// Round 9
// baseline (709.900 us; speedup 1.0000x reference)
//
#include <hip/hip_runtime.h>
#include <hip/hip_fp16.h>

#define NM 131072   // mol nodes
#define EM 524288   // mol edges
#define NG 4096     // graphs
#define DM 6        // mol in dim
#define NP 100000   // prot nodes
#define EP 1600000  // prot edges
#define DP 20       // prot in dim

static inline int cdiv(int a, int b){ return (a + b - 1) / b; }

__device__ __forceinline__ float leaky(float x){ return x > 0.f ? x : 0.2f * x; }

union H8 { float4 f4; __half2 h2[4]; };

// ================= bucketed CSR build (round-7, unchanged) =================
template<int CHUNK>
__global__ void k_coarse_hist(const int* __restrict__ dst, int* __restrict__ coarse,
                              int E, int K){
    __shared__ int lh[512];
    int t = threadIdx.x;
    for (int i = t; i < K; i += 256) lh[i] = 0;
    __syncthreads();
    int base = blockIdx.x * CHUNK;
    int end = min(base + CHUNK, E);
    for (int e = base + t; e < end; e += 256)
        atomicAdd(&lh[dst[e] >> 8], 1);
    __syncthreads();
    for (int i = t; i < K; i += 256)
        if (lh[i]) atomicAdd(&coarse[i], lh[i]);
}

__global__ void k_coarse_scan(const int* __restrict__ coarse, int* __restrict__ cstart,
                              int* __restrict__ cursor, int K, int E){
    int t = threadIdx.x, lane = t & 63, wid = t >> 6;
    int v0 = (t < K) ? coarse[t] : 0;
    int v = v0;
    #pragma unroll
    for (int off = 1; off < 64; off <<= 1) {
        int x = __shfl_up(v, off, 64);
        if (lane >= off) v += x;
    }
    __shared__ int ws[8];
    if (lane == 63) ws[wid] = v;
    __syncthreads();
    int add = 0;
    for (int w = 0; w < wid; w++) add += ws[w];
    int excl = v + add - v0;
    if (t < K) { cstart[t] = excl; cursor[t] = excl; }
    if (t == K - 1) cstart[K] = excl + v0;
}

template<int CHUNK, int EPT>
__global__ void k_part(const int* __restrict__ ei, int* __restrict__ cursor,
                       unsigned* __restrict__ buf, int E, int K){
    __shared__ int lh[512];
    __shared__ int lbase[512];
    int t = threadIdx.x;
    for (int i = t; i < K; i += 256) lh[i] = 0;
    __syncthreads();
    int base = blockIdx.x * CHUNK;
    int end = min(base + CHUNK, E);
    unsigned pay[EPT]; int bslot[EPT];
    int cnt = 0;
    for (int e = base + t; e < end; e += 256) {
        int u = ei[e], v = ei[E + e];
        int b = v >> 8;
        int ls = atomicAdd(&lh[b], 1);
        pay[cnt] = ((unsigned)(v & 255) << 24) | (unsigned)u;
        bslot[cnt] = (b << 13) | ls;
        cnt++;
    }
    __syncthreads();
    for (int i = t; i < K; i += 256)
        lbase[i] = lh[i] ? atomicAdd(&cursor[i], lh[i]) : 0;
    __syncthreads();
    for (int j = 0; j < cnt; j++) {
        int b = bslot[j] >> 13, ls = bslot[j] & 8191;
        buf[lbase[b] + ls] = pay[j];
    }
}

__global__ void k_fine(const unsigned* __restrict__ buf, const int* __restrict__ cstart,
                       int* __restrict__ rp, int* __restrict__ col, int n, int K){
    int k = blockIdx.x, t = threadIdx.x;
    int start = cstart[k], end = cstart[k + 1];
    __shared__ int cnt[256];
    __shared__ int cur[256];
    cnt[t] = 0;
    __syncthreads();
    for (int p = start + t; p < end; p += 256)
        atomicAdd(&cnt[buf[p] >> 24], 1);
    __syncthreads();
    int v0 = cnt[t];
    int lane = t & 63, wid = t >> 6;
    int v = v0;
    #pragma unroll
    for (int off = 1; off < 64; off <<= 1) {
        int x = __shfl_up(v, off, 64);
        if (lane >= off) v += x;
    }
    __shared__ int ws[4];
    if (lane == 63) ws[wid] = v;
    __syncthreads();
    int add = 0;
    for (int w = 0; w < wid; w++) add += ws[w];
    int excl = v + add - v0;
    int ofs = start + excl;
    cur[t] = ofs;
    int idx = (k << 8) + t;
    if (idx <= n) rp[idx] = ofs;
    if (k == K - 1 && t == 255) rp[n] = end;
    __syncthreads();
    for (int p = start + t; p < end; p += 256) {
        unsigned pk = buf[p];
        int slot = atomicAdd(&cur[pk >> 24], 1);
        col[slot] = (int)(pk & 0xFFFFFFu);
    }
}

template<int OBITS>
__global__ void k_pack(int* __restrict__ rp, int n){
    int i = blockIdx.x * 256 + threadIdx.x;
    if (i < n) {
        const unsigned M = (1u << OBITS) - 1;
        unsigned lo = ((unsigned)rp[i]) & M;
        unsigned hi = ((unsigned)rp[i + 1]) & M;
        rp[i] = (int)(lo | ((hi - lo) << OBITS));
    }
}

template<int OBITS>
__global__ void k_dinv(const int* __restrict__ rp, float* __restrict__ dinv, int n){
    int i = blockIdx.x * 256 + threadIdx.x;
    if (i < n) dinv[i] = rsqrtf((float)(((unsigned)rp[i] >> OBITS) + 1));
}

__global__ void k_wgcn(const int* __restrict__ col, const float* __restrict__ dinv,
                       float* __restrict__ w, int E){
    int p = blockIdx.x * 256 + threadIdx.x;
    if (p < E) w[p] = dinv[col[p]];
}

template<int OBITS>
__global__ void k_wcsr(const int* __restrict__ rp, const int* __restrict__ col,
                       const float* __restrict__ es, const float* __restrict__ ed_,
                       float* __restrict__ w, int n){
    int t = blockIdx.x * 256 + threadIdx.x;
    int node = t >> 4, q = t & 15;
    unsigned pk = (unsigned)rp[node];
    int s0 = (int)(pk & ((1u << OBITS) - 1));
    int deg = (int)(pk >> OBITS);
    float edv = ed_[node];
    for (int s = q; s < deg; s += 16) {
        int u = col[s0 + s];
        w[s0 + s] = __expf(leaky(es[u] + edv));
    }
}

__global__ void k_va(const float* __restrict__ W, const float* __restrict__ as_,
                     const float* __restrict__ ad_, float* __restrict__ va,
                     float* __restrict__ vd){
    int t = threadIdx.x;
    if (t < 20) {
        float s = 0.f;
        for (int j = 0; j < 64; j++) s += W[t * 64 + j] * as_[j];
        va[t] = s;
    } else if (t >= 32 && t < 52) {
        int k = t - 32;
        float s = 0.f;
        for (int j = 0; j < 64; j++) s += W[k * 64 + j] * ad_[j];
        vd[k] = s;
    }
}

// ---------------- prep: mol x -> padded 8-half rows ----------------
__global__ void k_prep_mol(const float* __restrict__ x, __half* __restrict__ x8, int n){
    int i = blockIdx.x * 256 + threadIdx.x;
    if (i >= n) return;
    H8 r;
    #pragma unroll
    for (int k = 0; k < 3; k++)
        r.h2[k] = __floats2half2_rn(x[i*6 + 2*k], x[i*6 + 2*k + 1]);
    r.h2[3] = __floats2half2_rn(0.f, 0.f);
    *(float4*)&x8[(size_t)i * 8] = r.f4;
}

// ---------------- prep: prot x -> padded 32-half rows + es/ed dots ----------------
__global__ void k_prep_prot(const float* __restrict__ x, const float* __restrict__ va,
                            const float* __restrict__ vd, __half* __restrict__ x32,
                            float* __restrict__ es, float* __restrict__ ed_, int n){
    int i = blockIdx.x * 256 + threadIdx.x;
    if (i >= n) return;
    float xv[20];
    float s = 0.f, d = 0.f;
    #pragma unroll
    for (int k = 0; k < 20; k++) {
        xv[k] = x[i*20 + k];
        s += xv[k] * va[k]; d += xv[k] * vd[k];
    }
    es[i] = s; ed_[i] = d;
    H8 r0, r1, r2, rz;
    #pragma unroll
    for (int k = 0; k < 4; k++) r0.h2[k] = __floats2half2_rn(xv[2*k],   xv[2*k+1]);
    #pragma unroll
    for (int k = 0; k < 4; k++) r1.h2[k] = __floats2half2_rn(xv[8+2*k], xv[9+2*k]);
    r2.h2[0] = __floats2half2_rn(xv[16], xv[17]);
    r2.h2[1] = __floats2half2_rn(xv[18], xv[19]);
    r2.h2[2] = __floats2half2_rn(0.f, 0.f);
    r2.h2[3] = __floats2half2_rn(0.f, 0.f);
    rz.h2[0] = rz.h2[1] = rz.h2[2] = rz.h2[3] = __floats2half2_rn(0.f, 0.f);
    *(float4*)&x32[(size_t)i * 32]      = r0.f4;
    *(float4*)&x32[(size_t)i * 32 + 8]  = r1.f4;
    *(float4*)&x32[(size_t)i * 32 + 16] = r2.f4;
    *(float4*)&x32[(size_t)i * 32 + 24] = rz.f4;
}

// ---------------- fused mol L1: gather(x8) + W1+b1+relu + W2 -> fp16 h2 ----------------
__global__ void k_mol_l1(const int* __restrict__ rp, const int* __restrict__ col,
                         const float* __restrict__ w, const __half* __restrict__ x8,
                         const float* __restrict__ dinv,
                         const float* __restrict__ W1, const float* __restrict__ b1,
                         const float* __restrict__ W2, __half* __restrict__ hout){
    __shared__ float W1s[6 * 64];
    __shared__ float W2s[64 * 64];
    __shared__ float aggL[4][8];
    __shared__ float Xs[4][68];
    int tid = threadIdx.x;
    for (int k = tid; k < 6 * 64; k += 256) W1s[k] = W1[k];
    for (int k = tid * 4; k < 4096; k += 1024)
        *(float4*)&W2s[k] = *(const float4*)&W2[k];
    int wvi = tid >> 6, l = tid & 63;
    int node = (blockIdx.x << 2) + wvi;
    unsigned pk = (unsigned)rp[node];
    int s0 = (int)(pk & 0xFFFFFu);
    int deg = (int)(pk >> 20);
    float dd = dinv[node];
    float acc[6] = {0.f,0.f,0.f,0.f,0.f,0.f};
    if (l == 0) {
        H8 r; r.f4 = *(const float4*)&x8[(size_t)node * 8];
        #pragma unroll
        for (int i = 0; i < 3; i++) {
            float2 f = __half22float2(r.h2[i]);
            acc[2*i] = dd * f.x; acc[2*i+1] = dd * f.y;
        }
    }
    for (int base = 0; base < deg; base += 64) {   // 64 slots in flight
        int s = base + l;
        int c = col[s0 + s]; float ww = w[s0 + s];  // +64 slack allocated
        int u = (s < deg) ? c : node;
        float wvv = (s < deg) ? ww : 0.f;
        H8 r; r.f4 = *(const float4*)&x8[(size_t)u * 8];
        #pragma unroll
        for (int i = 0; i < 3; i++) {
            float2 f = __half22float2(r.h2[i]);
            acc[2*i] += wvv * f.x; acc[2*i+1] += wvv * f.y;
        }
    }
    #pragma unroll
    for (int m = 1; m < 64; m <<= 1) {
        #pragma unroll
        for (int i = 0; i < 6; i++) acc[i] += __shfl_xor(acc[i], m, 64);
    }
    if (l == 0) {
        #pragma unroll
        for (int i = 0; i < 6; i++) aggL[wvi][i] = dd * acc[i];
    }
    __syncthreads();
    int j = l;
    float h1 = b1[j];
    #pragma unroll
    for (int k = 0; k < 6; k++) h1 += aggL[wvi][k] * W1s[k * 64 + j];
    h1 = fmaxf(h1, 0.f);
    Xs[wvi][j] = h1;
    float h2 = 0.f;
    #pragma unroll 8
    for (int k = 0; k < 64; k++) h2 += Xs[wvi][k] * W2s[k * 64 + j];
    hout[(size_t)node * 64 + j] = __float2half(h2);
}

// ---------------- fused prot L1: GAT gather(x32) + W1+b1+relu + W2 + att dots ----------------
__global__ void k_prot_l1(const int* __restrict__ rp, const int* __restrict__ col,
                          const float* __restrict__ w, const __half* __restrict__ x32,
                          float* __restrict__ es, float* __restrict__ ed_,
                          const float* __restrict__ W1, const float* __restrict__ b1,
                          const float* __restrict__ W2,
                          const float* __restrict__ as2, const float* __restrict__ ad2,
                          __half* __restrict__ hout){
    __shared__ float W1s[20 * 64];
    __shared__ float W2s[64 * 64];
    __shared__ float aggL[4][24];
    __shared__ float Xs[4][68];
    int tid = threadIdx.x;
    for (int k = tid; k < 20 * 64; k += 256) W1s[k] = W1[k];
    for (int k = tid * 4; k < 4096; k += 1024)
        *(float4*)&W2s[k] = *(const float4*)&W2[k];
    int wvi = tid >> 6, l = tid & 63;
    int g = l >> 2, q = l & 3;
    int node = (blockIdx.x << 2) + wvi;
    unsigned pk = (unsigned)rp[node];
    int s0 = (int)(pk & 0x1FFFFFu);
    int deg = (int)(pk >> 21);
    float selfw = __expf(leaky(es[node] + ed_[node]));
    float acc[8] = {0.f,0.f,0.f,0.f,0.f,0.f,0.f,0.f};
    float den = (l == 0) ? selfw : 0.f;
    if (g == 0 && q < 3) {
        H8 r; r.f4 = *(const float4*)&x32[(size_t)node * 32 + (q << 3)];
        #pragma unroll
        for (int i = 0; i < 4; i++) {
            float2 f = __half22float2(r.h2[i]);
            acc[2*i] = selfw * f.x; acc[2*i+1] = selfw * f.y;
        }
    }
    for (int base = 0; base < deg; base += 16) {   // 16 slots in flight
        int s = base + g;
        int c = col[s0 + s]; float ww = w[s0 + s];
        int u = (s < deg) ? c : node;
        float wvv = (s < deg) ? ww : 0.f;
        if (q < 3) {
            H8 r; r.f4 = *(const float4*)&x32[(size_t)u * 32 + (q << 3)];
            #pragma unroll
            for (int i = 0; i < 4; i++) {
                float2 f = __half22float2(r.h2[i]);
                acc[2*i] += wvv * f.x; acc[2*i+1] += wvv * f.y;
            }
        }
        if (q == 0) den += wvv;
    }
    #pragma unroll
    for (int m = 4; m <= 32; m <<= 1) {
        #pragma unroll
        for (int i = 0; i < 8; i++) acc[i] += __shfl_xor(acc[i], m, 64);
        den += __shfl_xor(den, m, 64);
    }
    den = __shfl(den, 0, 64);
    float inv = 1.f / den;
    if (g == 0 && q < 3) {
        #pragma unroll
        for (int i = 0; i < 8; i++) aggL[wvi][(q << 3) + i] = acc[i] * inv;
    }
    __syncthreads();
    int j = l;
    float h1 = b1[j];
    #pragma unroll
    for (int k = 0; k < 20; k++) h1 += aggL[wvi][k] * W1s[k * 64 + j];
    h1 = fmaxf(h1, 0.f);
    Xs[wvi][j] = h1;
    float h2 = 0.f;
    #pragma unroll 8
    for (int k = 0; k < 64; k++) h2 += Xs[wvi][k] * W2s[k * 64 + j];
    hout[(size_t)node * 64 + j] = __float2half(h2);
    float xa = h2 * as2[j], ya = h2 * ad2[j];
    #pragma unroll
    for (int m = 1; m < 64; m <<= 1) {
        xa += __shfl_xor(xa, m, 64);
        ya += __shfl_xor(ya, m, 64);
    }
    if (j == 0) { es[node] = xa; ed_[node] = ya; }
}

// ---------------- layer-2 gather, widened: 16 slots x 4 lanes x 32 B ----------------
template<int GAT, int OBITS>
__global__ void k_gather64hW(const int* __restrict__ rp, const int* __restrict__ col,
                             const float* __restrict__ w, const __half* __restrict__ hh,
                             const float* __restrict__ dinv, const float* __restrict__ es,
                             const float* __restrict__ ed_, const float* __restrict__ b,
                             float* __restrict__ out){
    int tid = threadIdx.x;
    int node = (blockIdx.x << 2) + (tid >> 6);
    int l = tid & 63, g = l >> 2, q = l & 3;
    unsigned pk = (unsigned)rp[node];
    int s0 = (int)(pk & ((1u << OBITS) - 1));
    int deg = (int)(pk >> OBITS);
    float selfw = GAT ? __expf(leaky(es[node] + ed_[node])) : dinv[node];
    float acc[16];
    #pragma unroll
    for (int i = 0; i < 16; i++) acc[i] = 0.f;
    float den = (l == 0) ? selfw : 0.f;
    if (g == 0) {
        H8 r0, r1;
        r0.f4 = *(const float4*)&hh[(size_t)node * 64 + (q << 4)];
        r1.f4 = *(const float4*)&hh[(size_t)node * 64 + (q << 4) + 8];
        #pragma unroll
        for (int i = 0; i < 4; i++) {
            float2 f0 = __half22float2(r0.h2[i]);
            float2 f1 = __half22float2(r1.h2[i]);
            acc[2*i]     = selfw * f0.x; acc[2*i+1]   = selfw * f0.y;
            acc[8+2*i]   = selfw * f1.x; acc[8+2*i+1] = selfw * f1.y;
        }
    }
    for (int base = 0; base < deg; base += 16) {
        int s = base + g;
        int c = col[s0 + s]; float ww = w[s0 + s];
        int u = (s < deg) ? c : node;
        float wvv = (s < deg) ? ww : 0.f;
        H8 r0, r1;
        r0.f4 = *(const float4*)&hh[(size_t)u * 64 + (q << 4)];
        r1.f4 = *(const float4*)&hh[(size_t)u * 64 + (q << 4) + 8];
        #pragma unroll
        for (int i = 0; i < 4; i++) {
            float2 f0 = __half22float2(r0.h2[i]);
            float2 f1 = __half22float2(r1.h2[i]);
            acc[2*i]     += wvv * f0.x; acc[2*i+1]   += wvv * f0.y;
            acc[8+2*i]   += wvv * f1.x; acc[8+2*i+1] += wvv * f1.y;
        }
        if (GAT && q == 0) den += wvv;
    }
    #pragma unroll
    for (int m = 4; m <= 32; m <<= 1) {
        #pragma unroll
        for (int i = 0; i < 16; i++) acc[i] += __shfl_xor(acc[i], m, 64);
        if (GAT) den += __shfl_xor(den, m, 64);
    }
    if (GAT) den = __shfl(den, 0, 64);   // uniform: all lanes execute
    if (g == 0) {
        float sc = GAT ? (1.f / den) : selfw;
        int f = q << 4;
        #pragma unroll
        for (int c4 = 0; c4 < 4; c4++) {
            float4 v;
            v.x = acc[4*c4]   * sc + b[f + 4*c4];
            v.y = acc[4*c4+1] * sc + b[f + 4*c4 + 1];
            v.z = acc[4*c4+2] * sc + b[f + 4*c4 + 2];
            v.w = acc[4*c4+3] * sc + b[f + 4*c4 + 3];
            *(float4*)&out[(size_t)node * 64 + f + 4*c4] = v;
        }
    }
}

// ---------------- mol pooling (round-8) ----------------
__global__ void k_hist(const int* __restrict__ dst, int* __restrict__ cnt, int E){
    int e = blockIdx.x * 256 + threadIdx.x;
    if (e < E) atomicAdd(&cnt[dst[e]], 1);
}
__global__ void k_filli(int* __restrict__ p, int v, int n){
    int i = blockIdx.x * 256 + threadIdx.x;
    if (i < n) p[i] = v;
}
__global__ void k_gstart(const int* __restrict__ batch, int* __restrict__ gstart, int n){
    int i = blockIdx.x * 256 + threadIdx.x;
    if (i < n) atomicMin(&gstart[batch[i]], i);
}
__global__ void k_segpool(const int* __restrict__ gstart, const int* __restrict__ gcnt,
                          const float* __restrict__ x, float* __restrict__ gsum){
    int gph = blockIdx.x, t = threadIdx.x;
    int rg = t >> 4, q = t & 15;
    int s = gstart[gph], c = gcnt[gph];
    float4 a = {0.f, 0.f, 0.f, 0.f};
    for (int i = rg; i < c; i += 4) {
        float4 v = *(const float4*)&x[(size_t)(s + i) * 64 + (q << 2)];
        a.x += v.x; a.y += v.y; a.z += v.z; a.w += v.w;
    }
    #pragma unroll
    for (int m = 16; m <= 32; m <<= 1) {
        a.x += __shfl_xor(a.x, m, 64);
        a.y += __shfl_xor(a.y, m, 64);
        a.z += __shfl_xor(a.z, m, 64);
        a.w += __shfl_xor(a.w, m, 64);
    }
    if (rg == 0) *(float4*)&gsum[gph * 64 + (q << 2)] = a;
}

// ---------------- prot pooling (round-8) ----------------
__global__ void k_pool_prot(const float* __restrict__ x, float* __restrict__ psum, int n){
    __shared__ float red[4][64];
    int t = threadIdx.x, lane = t & 63, wv = t >> 6;
    const float4* x4 = (const float4*)x;
    int total = n * 16;
    float4 a = {0.f, 0.f, 0.f, 0.f};
    for (int i = blockIdx.x * 256 + t; i < total; i += gridDim.x * 256) {
        float4 v = x4[i];
        a.x += v.x; a.y += v.y; a.z += v.z; a.w += v.w;
    }
    #pragma unroll
    for (int m = 16; m <= 32; m <<= 1) {
        a.x += __shfl_xor(a.x, m, 64);
        a.y += __shfl_xor(a.y, m, 64);
        a.z += __shfl_xor(a.z, m, 64);
        a.w += __shfl_xor(a.w, m, 64);
    }
    if (lane < 16) *(float4*)&red[wv][lane << 2] = a;
    __syncthreads();
    if (t < 64) {
        float s = red[0][t] + red[1][t] + red[2][t] + red[3][t];
        atomicAdd(&psum[t], s);
    }
}

// ---------------- fused classifier ----------------
__global__ void k_cls(const float* __restrict__ gsum, const int* __restrict__ gcnt,
                      const float* __restrict__ psum, const float* __restrict__ W1,
                      const float* __restrict__ b1, const float* __restrict__ w2,
                      const float* __restrict__ b2, float* __restrict__ out){
    __shared__ float W1s[128 * 64];
    int tid = threadIdx.x;
    for (int k = tid; k < 128 * 64; k += 256) W1s[k] = W1[k];
    __syncthreads();
    int g = blockIdx.x * 4 + (tid >> 6);
    int j = tid & 63;
    float inv = 1.0f / fmaxf((float)gcnt[g], 1.0f);
    const float invp = 1.0f / (float)NP;
    float acc = b1[j];
    #pragma unroll 8
    for (int k = 0; k < 64; k++) acc += (gsum[g * 64 + k] * inv) * W1s[k * 64 + j];
    #pragma unroll 8
    for (int k = 0; k < 64; k++) acc += (psum[k] * invp) * W1s[(64 + k) * 64 + j];
    float v = fmaxf(acc, 0.f) * w2[j];
    #pragma unroll
    for (int off = 32; off > 0; off >>= 1) v += __shfl_down(v, off, 64);
    if (j == 0) out[g] = 1.0f / (1.0f + expf(-(v + b2[0])));
}

extern "C" void kernel_launch(void* const* d_in, const int* in_sizes, int n_in,
                              void* d_out, int out_size, void* d_ws, size_t ws_size,
                              hipStream_t stream) {
    const float* mol_x   = (const float*)d_in[0];
    const int*   mol_ei  = (const int*)d_in[1];
    const int*   mol_bat = (const int*)d_in[2];
    const float* prot_x  = (const float*)d_in[3];
    const int*   prot_ei = (const int*)d_in[4];
    const float* gcn_w1  = (const float*)d_in[5];
    const float* gcn_b1  = (const float*)d_in[6];
    const float* gcn_w2  = (const float*)d_in[7];
    const float* gcn_b2  = (const float*)d_in[8];
    const float* gat_w1  = (const float*)d_in[9];
    const float* gat_as1 = (const float*)d_in[10];
    const float* gat_ad1 = (const float*)d_in[11];
    const float* gat_b1  = (const float*)d_in[12];
    const float* gat_w2  = (const float*)d_in[13];
    const float* gat_as2 = (const float*)d_in[14];
    const float* gat_ad2 = (const float*)d_in[15];
    const float* gat_b2  = (const float*)d_in[16];
    const float* cls_w1  = (const float*)d_in[17];
    const float* cls_b1  = (const float*)d_in[18];
    const float* cls_w2  = (const float*)d_in[19];
    const float* cls_b2  = (const float*)d_in[20];
    float* out = (float*)d_out;

    float* ws_f = (float*)d_ws;

    // ---- persistent tail ----
    float* T      = ws_f + 16777216;
    float* gsum   = T;                       // 262,144
    int*   gcntI  = (int*)(T + 262144);      // 4,096
    float* psum   = T + 266240;              // 64
    int*   gstart = (int*)(T + 266304);      // 4,096
    float* va     = T + 270400;              // 32
    float* vd     = T + 270432;              // 32
    int*   coarse = (int*)(T + 270464);      // 512
    int*   cstart = (int*)(T + 270976);      // 513
    int*   cursor = (int*)(T + 271489);      // 512

    // ---- mol-phase layout ----
    float*    molout = ws_f;                             // [0, 8388608)
    unsigned* bufM   = (unsigned*)ws_f;                  // EM (dead before molout)
    __half*   h2hM   = (__half*)(ws_f + 8388608);        // [8388608, 12582912)
    int*      molCOL = (int*)(ws_f + 12582912);          // EM+64 -> 13107264
    int*      molRP  = (int*)(ws_f + 13107264);          // NM+1
    float*    dinvM  = ws_f + 13238352;                  // NM
    float*    wM     = ws_f + 13369440;                  // EM+64 -> 13893792
    __half*   x8h    = (__half*)(ws_f + 13893792);       // NM*8 halves -> 14418080

    // ---- prot-phase layout (mol fully done first) ----
    float*    protout = ws_f;                            // [0, 6400000)
    unsigned* bufP    = (unsigned*)ws_f;                 // EP (dead before protout)
    __half*   h2hP    = (__half*)(ws_f + 6400000);       // [6400000, 9600000)
    int*      protCOL = (int*)(ws_f + 9600000);          // EP+64 -> 11200064
    int*      protRP  = (int*)(ws_f + 11200064);         // NP+1
    float*    es      = ws_f + 11300080;                 // NP
    float*    ed_     = ws_f + 11400080;                 // NP
    float*    wP      = ws_f + 11500080;                 // EP+64 -> 13100144
    __half*   x32h    = (__half*)(ws_f + 13100144);      // NP*32 halves -> 14700144

    const int KM = 512;   // NM/256
    const int KPb = 391;  // cdiv(NP,256)

    // ================= mol branch =================
    hipMemsetAsync(coarse, 0, (size_t)KM * sizeof(int), stream);
    k_coarse_hist<2048><<<cdiv(EM,2048),256,0,stream>>>(mol_ei + EM, coarse, EM, KM);
    k_coarse_scan<<<1,512,0,stream>>>(coarse, cstart, cursor, KM, EM);
    k_part<2048,8><<<cdiv(EM,2048),256,0,stream>>>(mol_ei, cursor, bufM, EM, KM);
    k_fine<<<KM,256,0,stream>>>(bufM, cstart, molRP, molCOL, NM, KM);
    k_pack<20><<<cdiv(NM,256),256,0,stream>>>(molRP, NM);
    k_dinv<20><<<cdiv(NM,256),256,0,stream>>>(molRP, dinvM, NM);
    k_wgcn<<<cdiv(EM,256),256,0,stream>>>(molCOL, dinvM, wM, EM);
    k_prep_mol<<<cdiv(NM,256),256,0,stream>>>(mol_x, x8h, NM);
    k_mol_l1<<<NM/4,256,0,stream>>>(molRP, molCOL, wM, x8h, dinvM, gcn_w1, gcn_b1, gcn_w2, h2hM);
    k_gather64hW<0,20><<<NM/4,256,0,stream>>>(molRP, molCOL, wM, h2hM, dinvM, nullptr, nullptr, gcn_b2, molout);
    k_filli<<<cdiv(NG,256),256,0,stream>>>(gstart, NM, NG);
    hipMemsetAsync(gcntI, 0, (size_t)NG * sizeof(int), stream);
    k_hist<<<cdiv(NM,256),256,0,stream>>>(mol_bat, gcntI, NM);
    k_gstart<<<cdiv(NM,256),256,0,stream>>>(mol_bat, gstart, NM);
    k_segpool<<<NG,64,0,stream>>>(gstart, gcntI, molout, gsum);

    // ================= prot branch =================
    hipMemsetAsync(coarse, 0, (size_t)KPb * sizeof(int), stream);
    k_coarse_hist<4096><<<cdiv(EP,4096),256,0,stream>>>(prot_ei + EP, coarse, EP, KPb);
    k_coarse_scan<<<1,512,0,stream>>>(coarse, cstart, cursor, KPb, EP);
    k_part<4096,16><<<cdiv(EP,4096),256,0,stream>>>(prot_ei, cursor, bufP, EP, KPb);
    k_fine<<<KPb,256,0,stream>>>(bufP, cstart, protRP, protCOL, NP, KPb);
    k_pack<21><<<cdiv(NP,256),256,0,stream>>>(protRP, NP);
    k_va<<<1,64,0,stream>>>(gat_w1, gat_as1, gat_ad1, va, vd);
    k_prep_prot<<<cdiv(NP,256),256,0,stream>>>(prot_x, va, vd, x32h, es, ed_, NP);
    k_wcsr<21><<<cdiv(NP*16,256),256,0,stream>>>(protRP, protCOL, es, ed_, wP, NP);
    k_prot_l1<<<NP/4,256,0,stream>>>(protRP, protCOL, wP, x32h, es, ed_, gat_w1, gat_b1, gat_w2, gat_as2, gat_ad2, h2hP);
    k_wcsr<21><<<cdiv(NP*16,256),256,0,stream>>>(protRP, protCOL, es, ed_, wP, NP);
    k_gather64hW<1,21><<<NP/4,256,0,stream>>>(protRP, protCOL, wP, h2hP, nullptr, es, ed_, gat_b2, protout);
    hipMemsetAsync(psum, 0, 64 * sizeof(float), stream);
    k_pool_prot<<<1024,256,0,stream>>>(protout, psum, NP);

    // ================= classifier =================
    k_cls<<<NG/4,256,0,stream>>>(gsum, gcntI, psum, cls_w1, cls_b1, cls_w2, cls_b2, out);
}

// Round 10
// 532.894 us; speedup vs baseline: 1.3322x; 1.3322x over previous
//
#include <hip/hip_runtime.h>
#include <hip/hip_fp16.h>

#define NM 131072   // mol nodes
#define EM 524288   // mol edges
#define NG 4096     // graphs
#define DM 6        // mol in dim
#define NP 100000   // prot nodes
#define EP 1600000  // prot edges
#define DP 20       // prot in dim

static inline int cdiv(int a, int b){ return (a + b - 1) / b; }

__device__ __forceinline__ float leaky(float x){ return x > 0.f ? x : 0.2f * x; }

union H8 { float4 f4; __half2 h2[4]; };

// ================= bucketed CSR build =================
template<int CHUNK>
__global__ void k_coarse_hist(const int* __restrict__ dst, int* __restrict__ coarse,
                              int E, int K){
    __shared__ int lh[512];
    int t = threadIdx.x;
    for (int i = t; i < K; i += 256) lh[i] = 0;
    __syncthreads();
    int base = blockIdx.x * CHUNK;
    int end = min(base + CHUNK, E);
    for (int e = base + t; e < end; e += 256)
        atomicAdd(&lh[dst[e] >> 8], 1);
    __syncthreads();
    for (int i = t; i < K; i += 256)
        if (lh[i]) atomicAdd(&coarse[i], lh[i]);
}

__global__ void k_coarse_scan(const int* __restrict__ coarse, int* __restrict__ cstart,
                              int* __restrict__ cursor, int K, int E){
    int t = threadIdx.x, lane = t & 63, wid = t >> 6;
    int v0 = (t < K) ? coarse[t] : 0;
    int v = v0;
    #pragma unroll
    for (int off = 1; off < 64; off <<= 1) {
        int x = __shfl_up(v, off, 64);
        if (lane >= off) v += x;
    }
    __shared__ int ws[8];
    if (lane == 63) ws[wid] = v;
    __syncthreads();
    int add = 0;
    for (int w = 0; w < wid; w++) add += ws[w];
    int excl = v + add - v0;
    if (t < K) { cstart[t] = excl; cursor[t] = excl; }
    if (t == K - 1) cstart[K] = excl + v0;
}

template<int CHUNK, int EPT>
__global__ void k_part(const int* __restrict__ ei, int* __restrict__ cursor,
                       unsigned* __restrict__ buf, int E, int K){
    __shared__ int lh[512];
    __shared__ int lbase[512];
    int t = threadIdx.x;
    for (int i = t; i < K; i += 256) lh[i] = 0;
    __syncthreads();
    int base = blockIdx.x * CHUNK;
    int end = min(base + CHUNK, E);
    unsigned pay[EPT]; int bslot[EPT];
    int cnt = 0;
    for (int e = base + t; e < end; e += 256) {
        int u = ei[e], v = ei[E + e];
        int b = v >> 8;
        int ls = atomicAdd(&lh[b], 1);
        pay[cnt] = ((unsigned)(v & 255) << 24) | (unsigned)u;
        bslot[cnt] = (b << 13) | ls;
        cnt++;
    }
    __syncthreads();
    for (int i = t; i < K; i += 256)
        lbase[i] = lh[i] ? atomicAdd(&cursor[i], lh[i]) : 0;
    __syncthreads();
    for (int j = 0; j < cnt; j++) {
        int b = bslot[j] >> 13, ls = bslot[j] & 8191;
        buf[lbase[b] + ls] = pay[j];
    }
}

// fine: writes PACKED rp (start | deg<<OBITS) and optionally dinv directly
template<int OBITS, int DINV>
__global__ void k_fine(const unsigned* __restrict__ buf, const int* __restrict__ cstart,
                       int* __restrict__ rp, int* __restrict__ col,
                       float* __restrict__ dinv, int n, int K){
    int k = blockIdx.x, t = threadIdx.x;
    int start = cstart[k], end = cstart[k + 1];
    __shared__ int cnt[256];
    __shared__ int cur[256];
    cnt[t] = 0;
    __syncthreads();
    for (int p = start + t; p < end; p += 256)
        atomicAdd(&cnt[buf[p] >> 24], 1);
    __syncthreads();
    int v0 = cnt[t];
    int lane = t & 63, wid = t >> 6;
    int v = v0;
    #pragma unroll
    for (int off = 1; off < 64; off <<= 1) {
        int x = __shfl_up(v, off, 64);
        if (lane >= off) v += x;
    }
    __shared__ int ws[4];
    if (lane == 63) ws[wid] = v;
    __syncthreads();
    int add = 0;
    for (int w = 0; w < wid; w++) add += ws[w];
    int excl = v + add - v0;
    int ofs = start + excl;
    cur[t] = ofs;
    int idx = (k << 8) + t;
    if (idx < n) {
        rp[idx] = (int)((unsigned)ofs | ((unsigned)v0 << OBITS));
        if (DINV) dinv[idx] = rsqrtf((float)(v0 + 1));
    }
    __syncthreads();
    for (int p = start + t; p < end; p += 256) {
        unsigned pk = buf[p];
        int slot = atomicAdd(&cur[pk >> 24], 1);
        col[slot] = (int)(pk & 0xFFFFFFu);
    }
}

__global__ void k_wgcn(const int* __restrict__ col, const float* __restrict__ dinv,
                       float* __restrict__ w, int E){
    int p = blockIdx.x * 256 + threadIdx.x;
    if (p < E) w[p] = dinv[col[p]];
}

template<int OBITS>
__global__ void k_wcsr(const int* __restrict__ rp, const int* __restrict__ col,
                       const float* __restrict__ es, const float* __restrict__ ed_,
                       float* __restrict__ w, int n){
    int t = blockIdx.x * 256 + threadIdx.x;
    int node = t >> 4, q = t & 15;
    unsigned pk = (unsigned)rp[node];
    int s0 = (int)(pk & ((1u << OBITS) - 1));
    int deg = (int)(pk >> OBITS);
    float edv = ed_[node];
    for (int s = q; s < deg; s += 16) {
        int u = col[s0 + s];
        w[s0 + s] = __expf(leaky(es[u] + edv));
    }
}

// ---------------- prep: mol x -> padded 8-half rows ----------------
__global__ void k_prep_mol(const float* __restrict__ x, __half* __restrict__ x8, int n){
    int i = blockIdx.x * 256 + threadIdx.x;
    if (i >= n) return;
    H8 r;
    #pragma unroll
    for (int k = 0; k < 3; k++)
        r.h2[k] = __floats2half2_rn(x[i*6 + 2*k], x[i*6 + 2*k + 1]);
    r.h2[3] = __floats2half2_rn(0.f, 0.f);
    *(float4*)&x8[(size_t)i * 8] = r.f4;
}

// ---------------- prep: prot x -> padded 32-half rows + es/ed dots (va/vd in LDS) ----------------
__global__ void k_prep_prot(const float* __restrict__ x, const float* __restrict__ W1,
                            const float* __restrict__ as_, const float* __restrict__ ad_,
                            __half* __restrict__ x32, float* __restrict__ es,
                            float* __restrict__ ed_, int n){
    __shared__ float vas[20], vds[20];
    int t = threadIdx.x;
    if (t < 20) {
        float s = 0.f;
        for (int j = 0; j < 64; j++) s += W1[t * 64 + j] * as_[j];
        vas[t] = s;
    } else if (t >= 32 && t < 52) {
        int k = t - 32;
        float s = 0.f;
        for (int j = 0; j < 64; j++) s += W1[k * 64 + j] * ad_[j];
        vds[k] = s;
    }
    __syncthreads();
    int i = blockIdx.x * 256 + t;
    if (i >= n) return;
    float xv[20];
    float s = 0.f, d = 0.f;
    #pragma unroll
    for (int k = 0; k < 20; k++) {
        xv[k] = x[i*20 + k];
        s += xv[k] * vas[k]; d += xv[k] * vds[k];
    }
    es[i] = s; ed_[i] = d;
    H8 r0, r1, r2, rz;
    #pragma unroll
    for (int k = 0; k < 4; k++) r0.h2[k] = __floats2half2_rn(xv[2*k],   xv[2*k+1]);
    #pragma unroll
    for (int k = 0; k < 4; k++) r1.h2[k] = __floats2half2_rn(xv[8+2*k], xv[9+2*k]);
    r2.h2[0] = __floats2half2_rn(xv[16], xv[17]);
    r2.h2[1] = __floats2half2_rn(xv[18], xv[19]);
    r2.h2[2] = __floats2half2_rn(0.f, 0.f);
    r2.h2[3] = __floats2half2_rn(0.f, 0.f);
    rz.h2[0] = rz.h2[1] = rz.h2[2] = rz.h2[3] = __floats2half2_rn(0.f, 0.f);
    *(float4*)&x32[(size_t)i * 32]      = r0.f4;
    *(float4*)&x32[(size_t)i * 32 + 8]  = r1.f4;
    *(float4*)&x32[(size_t)i * 32 + 16] = r2.f4;
    *(float4*)&x32[(size_t)i * 32 + 24] = rz.f4;
}

// ---------------- mol L1 gather: 64 slots in flight, 16-B rows, 1 wave/node ----------------
__global__ void k_gather_x8(const int* __restrict__ rp, const int* __restrict__ col,
                            const float* __restrict__ w, const __half* __restrict__ x8,
                            const float* __restrict__ dinv, float* __restrict__ agg){
    int tid = threadIdx.x;
    int node = (blockIdx.x << 2) + (tid >> 6);
    int l = tid & 63;
    unsigned pk = (unsigned)rp[node];
    int s0 = (int)(pk & 0xFFFFFu);
    int deg = (int)(pk >> 20);
    float dd = dinv[node];
    float acc[6] = {0.f,0.f,0.f,0.f,0.f,0.f};
    if (l == 0) {
        H8 r; r.f4 = *(const float4*)&x8[(size_t)node * 8];
        #pragma unroll
        for (int i = 0; i < 3; i++) {
            float2 f = __half22float2(r.h2[i]);
            acc[2*i] = dd * f.x; acc[2*i+1] = dd * f.y;
        }
    }
    for (int base = 0; base < deg; base += 64) {
        int s = base + l;
        int c = col[s0 + s]; float ww = w[s0 + s];   // +64 slack allocated
        int u = (s < deg) ? c : node;
        float wvv = (s < deg) ? ww : 0.f;
        H8 r; r.f4 = *(const float4*)&x8[(size_t)u * 8];
        #pragma unroll
        for (int i = 0; i < 3; i++) {
            float2 f = __half22float2(r.h2[i]);
            acc[2*i] += wvv * f.x; acc[2*i+1] += wvv * f.y;
        }
    }
    #pragma unroll
    for (int m = 1; m < 64; m <<= 1) {
        #pragma unroll
        for (int i = 0; i < 6; i++) acc[i] += __shfl_xor(acc[i], m, 64);
    }
    if (l == 0) {
        *(float2*)&agg[(size_t)node * 6]     = make_float2(dd * acc[0], dd * acc[1]);
        *(float2*)&agg[(size_t)node * 6 + 2] = make_float2(dd * acc[2], dd * acc[3]);
        *(float2*)&agg[(size_t)node * 6 + 4] = make_float2(dd * acc[4], dd * acc[5]);
    }
}

// ---------------- prot L1 GAT gather: 16 slots x 4 lanes, 64-B rows ----------------
__global__ void k_gather_x32(const int* __restrict__ rp, const int* __restrict__ col,
                             const float* __restrict__ w, const __half* __restrict__ x32,
                             const float* __restrict__ es, const float* __restrict__ ed_,
                             float* __restrict__ agg){
    int tid = threadIdx.x;
    int node = (blockIdx.x << 2) + (tid >> 6);
    int l = tid & 63, g = l >> 2, q = l & 3;
    unsigned pk = (unsigned)rp[node];
    int s0 = (int)(pk & 0x1FFFFFu);
    int deg = (int)(pk >> 21);
    float selfw = __expf(leaky(es[node] + ed_[node]));
    float acc[8] = {0.f,0.f,0.f,0.f,0.f,0.f,0.f,0.f};
    float den = (l == 0) ? selfw : 0.f;
    if (g == 0 && q < 3) {
        H8 r; r.f4 = *(const float4*)&x32[(size_t)node * 32 + (q << 3)];
        #pragma unroll
        for (int i = 0; i < 4; i++) {
            float2 f = __half22float2(r.h2[i]);
            acc[2*i] = selfw * f.x; acc[2*i+1] = selfw * f.y;
        }
    }
    for (int base = 0; base < deg; base += 16) {
        int s = base + g;
        int c = col[s0 + s]; float ww = w[s0 + s];
        int u = (s < deg) ? c : node;
        float wvv = (s < deg) ? ww : 0.f;
        if (q < 3) {
            H8 r; r.f4 = *(const float4*)&x32[(size_t)u * 32 + (q << 3)];
            #pragma unroll
            for (int i = 0; i < 4; i++) {
                float2 f = __half22float2(r.h2[i]);
                acc[2*i] += wvv * f.x; acc[2*i+1] += wvv * f.y;
            }
        }
        if (q == 0) den += wvv;
    }
    #pragma unroll
    for (int m = 4; m <= 32; m <<= 1) {
        #pragma unroll
        for (int i = 0; i < 8; i++) acc[i] += __shfl_xor(acc[i], m, 64);
        den += __shfl_xor(den, m, 64);
    }
    den = __shfl(den, 0, 64);
    float inv = 1.f / den;
    if (g == 0) {
        if (q < 2) {
            float4 v0 = make_float4(acc[0]*inv, acc[1]*inv, acc[2]*inv, acc[3]*inv);
            float4 v1 = make_float4(acc[4]*inv, acc[5]*inv, acc[6]*inv, acc[7]*inv);
            *(float4*)&agg[(size_t)node * 20 + (q << 3)]     = v0;
            *(float4*)&agg[(size_t)node * 20 + (q << 3) + 4] = v1;
        } else if (q == 2) {
            float4 v0 = make_float4(acc[0]*inv, acc[1]*inv, acc[2]*inv, acc[3]*inv);
            *(float4*)&agg[(size_t)node * 20 + 16] = v0;
        }
    }
}

// ---------------- agg[n,D] @ W[D,64] + b (+relu): 16 nodes/block ----------------
template<int D, int RELU>
__global__ void k_xw_small16(const float* __restrict__ x, const float* __restrict__ W,
                             const float* __restrict__ b, float* __restrict__ h, int n){
    __shared__ float Ws[D * 64];
    __shared__ float Xs[16][D];
    int tid = threadIdx.x;
    for (int k = tid; k < D * 64; k += 256) Ws[k] = W[k];
    int nd = tid >> 4, q = tid & 15;
    int node = blockIdx.x * 16 + nd;
    if (node < n)
        for (int k = q; k < D; k += 16) Xs[nd][k] = x[(size_t)node * D + k];
    __syncthreads();
    if (node >= n) return;
    float4 acc = *(const float4*)&b[q << 2];
    #pragma unroll
    for (int k = 0; k < D; k++) {
        float xk = Xs[nd][k];
        float4 w4 = *(const float4*)&Ws[(k << 6) + (q << 2)];
        acc.x += xk * w4.x; acc.y += xk * w4.y; acc.z += xk * w4.z; acc.w += xk * w4.w;
    }
    if (RELU) {
        acc.x = fmaxf(acc.x, 0.f); acc.y = fmaxf(acc.y, 0.f);
        acc.z = fmaxf(acc.z, 0.f); acc.w = fmaxf(acc.w, 0.f);
    }
    *(float4*)&h[(size_t)node * 64 + (q << 2)] = acc;
}

// ---------------- x[n,64] @ W[64,64] -> half (+ fused attention dots) ----------------
template<int ATT>
__global__ void k_xw64h(const float* __restrict__ x, const float* __restrict__ W,
                        const float* __restrict__ as_, const float* __restrict__ ad_,
                        __half* __restrict__ hout, float* __restrict__ es,
                        float* __restrict__ ed_, int n){
    __shared__ float Ws[64 * 64];
    __shared__ float Xs[16 * 68];
    int tid = threadIdx.x;
    for (int k = tid * 4; k < 4096; k += 1024)
        *(float4*)&Ws[k] = *(const float4*)&W[k];
    int nd = tid >> 4, q = tid & 15;
    int node = blockIdx.x * 16 + nd;
    if (node < n)
        *(float4*)&Xs[nd * 68 + (q << 2)] = *(const float4*)&x[(size_t)node * 64 + (q << 2)];
    __syncthreads();
    if (node >= n) return;
    float4 acc = {0.f, 0.f, 0.f, 0.f};
    #pragma unroll 8
    for (int k = 0; k < 64; k++) {
        float xk = Xs[nd * 68 + k];
        float4 w4 = *(const float4*)&Ws[(k << 6) + (q << 2)];
        acc.x += xk * w4.x; acc.y += xk * w4.y; acc.z += xk * w4.z; acc.w += xk * w4.w;
    }
    union { __half2 h2[2]; float2 f2; } u;
    u.h2[0] = __floats2half2_rn(acc.x, acc.y);
    u.h2[1] = __floats2half2_rn(acc.z, acc.w);
    *(float2*)&hout[(size_t)node * 64 + (q << 2)] = u.f2;
    if (ATT) {
        int f = q << 2;
        float xa = acc.x * as_[f] + acc.y * as_[f + 1] + acc.z * as_[f + 2] + acc.w * as_[f + 3];
        float ya = acc.x * ad_[f] + acc.y * ad_[f + 1] + acc.z * ad_[f + 2] + acc.w * ad_[f + 3];
        #pragma unroll
        for (int m = 1; m < 16; m <<= 1) {
            xa += __shfl_xor(xa, m, 16);
            ya += __shfl_xor(ya, m, 16);
        }
        if (q == 0) { es[node] = xa; ed_[node] = ya; }
    }
}

// ---------------- layer-2 gather over half rows: 8 slots x 8 lanes (round-8 proven) ----------------
template<int GAT, int OBITS>
__global__ void k_gather64h(const int* __restrict__ rp, const int* __restrict__ col,
                            const float* __restrict__ w, const __half* __restrict__ hh,
                            const float* __restrict__ dinv, const float* __restrict__ es,
                            const float* __restrict__ ed_, const float* __restrict__ b,
                            float* __restrict__ out){
    int tid = threadIdx.x;
    int node = (blockIdx.x << 2) + (tid >> 6);
    int l = tid & 63, g = l >> 3, q = l & 7;
    unsigned pk = (unsigned)rp[node];
    int s0 = (int)(pk & ((1u << OBITS) - 1));
    int deg = (int)(pk >> OBITS);
    float acc[8] = {0.f,0.f,0.f,0.f,0.f,0.f,0.f,0.f};
    float den = 0.f;
    float selfw = GAT ? __expf(leaky(es[node] + ed_[node])) : dinv[node];
    if (g == 0) {
        H8 r; r.f4 = *(const float4*)&hh[(size_t)node * 64 + (q << 3)];
        #pragma unroll
        for (int i = 0; i < 4; i++) {
            float2 f = __half22float2(r.h2[i]);
            acc[2*i]     = selfw * f.x;
            acc[2*i + 1] = selfw * f.y;
        }
        den = selfw;
    }
    for (int base = 0; base < deg; base += 8) {
        int s = base + g;
        int c = col[s0 + s]; float ww = w[s0 + s];
        int u = (s < deg) ? c : node;
        float wvv = (s < deg) ? ww : 0.f;
        H8 r; r.f4 = *(const float4*)&hh[(size_t)u * 64 + (q << 3)];
        #pragma unroll
        for (int i = 0; i < 4; i++) {
            float2 f = __half22float2(r.h2[i]);
            acc[2*i]     += wvv * f.x;
            acc[2*i + 1] += wvv * f.y;
        }
        if (GAT) den += wvv;
    }
    #pragma unroll
    for (int m = 8; m <= 32; m <<= 1) {
        #pragma unroll
        for (int i = 0; i < 8; i++) acc[i] += __shfl_xor(acc[i], m, 64);
        if (GAT) den += __shfl_xor(den, m, 64);
    }
    if (g == 0) {
        float sc = GAT ? (1.f / den) : selfw;
        int f = q << 3;
        float4 v0, v1;
        v0.x = acc[0]*sc + b[f];     v0.y = acc[1]*sc + b[f+1];
        v0.z = acc[2]*sc + b[f+2];   v0.w = acc[3]*sc + b[f+3];
        v1.x = acc[4]*sc + b[f+4];   v1.y = acc[5]*sc + b[f+5];
        v1.z = acc[6]*sc + b[f+6];   v1.w = acc[7]*sc + b[f+7];
        *(float4*)&out[(size_t)node * 64 + f]     = v0;
        *(float4*)&out[(size_t)node * 64 + f + 4] = v1;
    }
}

// ---------------- mol pooling: boundary-based segments (batch sorted) ----------------
__global__ void k_segbounds(const int* __restrict__ batch, int* __restrict__ gstart,
                            int* __restrict__ gend, int n){
    int i = blockIdx.x * 256 + threadIdx.x;
    if (i >= n) return;
    int g = batch[i];
    if (i == 0 || batch[i - 1] != g) gstart[g] = i;
    if (i == n - 1 || batch[i + 1] != g) gend[g] = i + 1;
}
__global__ void k_segpool(const int* __restrict__ gstart, const int* __restrict__ gend,
                          const float* __restrict__ x, float* __restrict__ gsum){
    int gph = blockIdx.x, t = threadIdx.x;
    int rg = t >> 4, q = t & 15;
    int s = gstart[gph], c = gend[gph] - gstart[gph];
    float4 a = {0.f, 0.f, 0.f, 0.f};
    for (int i = rg; i < c; i += 4) {
        float4 v = *(const float4*)&x[(size_t)(s + i) * 64 + (q << 2)];
        a.x += v.x; a.y += v.y; a.z += v.z; a.w += v.w;
    }
    #pragma unroll
    for (int m = 16; m <= 32; m <<= 1) {
        a.x += __shfl_xor(a.x, m, 64);
        a.y += __shfl_xor(a.y, m, 64);
        a.z += __shfl_xor(a.z, m, 64);
        a.w += __shfl_xor(a.w, m, 64);
    }
    if (rg == 0) *(float4*)&gsum[gph * 64 + (q << 2)] = a;
}

// ---------------- prot pooling ----------------
__global__ void k_pool_prot(const float* __restrict__ x, float* __restrict__ psum, int n){
    __shared__ float red[4][64];
    int t = threadIdx.x, lane = t & 63, wv = t >> 6;
    const float4* x4 = (const float4*)x;
    int total = n * 16;
    float4 a = {0.f, 0.f, 0.f, 0.f};
    for (int i = blockIdx.x * 256 + t; i < total; i += gridDim.x * 256) {
        float4 v = x4[i];
        a.x += v.x; a.y += v.y; a.z += v.z; a.w += v.w;
    }
    #pragma unroll
    for (int m = 16; m <= 32; m <<= 1) {
        a.x += __shfl_xor(a.x, m, 64);
        a.y += __shfl_xor(a.y, m, 64);
        a.z += __shfl_xor(a.z, m, 64);
        a.w += __shfl_xor(a.w, m, 64);
    }
    if (lane < 16) *(float4*)&red[wv][lane << 2] = a;
    __syncthreads();
    if (t < 64) {
        float s = red[0][t] + red[1][t] + red[2][t] + red[3][t];
        atomicAdd(&psum[t], s);
    }
}

// ---------------- fused classifier ----------------
__global__ void k_cls(const float* __restrict__ gsum, const int* __restrict__ gstart,
                      const int* __restrict__ gend, const float* __restrict__ psum,
                      const float* __restrict__ W1, const float* __restrict__ b1,
                      const float* __restrict__ w2, const float* __restrict__ b2,
                      float* __restrict__ out){
    __shared__ float W1s[128 * 64];
    int tid = threadIdx.x;
    for (int k = tid; k < 128 * 64; k += 256) W1s[k] = W1[k];
    __syncthreads();
    int g = blockIdx.x * 4 + (tid >> 6);
    int j = tid & 63;
    float cntf = (float)(gend[g] - gstart[g]);
    float inv = 1.0f / fmaxf(cntf, 1.0f);
    const float invp = 1.0f / (float)NP;
    float acc = b1[j];
    #pragma unroll 8
    for (int k = 0; k < 64; k++) acc += (gsum[g * 64 + k] * inv) * W1s[k * 64 + j];
    #pragma unroll 8
    for (int k = 0; k < 64; k++) acc += (psum[k] * invp) * W1s[(64 + k) * 64 + j];
    float v = fmaxf(acc, 0.f) * w2[j];
    #pragma unroll
    for (int off = 32; off > 0; off >>= 1) v += __shfl_down(v, off, 64);
    if (j == 0) out[g] = 1.0f / (1.0f + expf(-(v + b2[0])));
}

extern "C" void kernel_launch(void* const* d_in, const int* in_sizes, int n_in,
                              void* d_out, int out_size, void* d_ws, size_t ws_size,
                              hipStream_t stream) {
    const float* mol_x   = (const float*)d_in[0];
    const int*   mol_ei  = (const int*)d_in[1];
    const int*   mol_bat = (const int*)d_in[2];
    const float* prot_x  = (const float*)d_in[3];
    const int*   prot_ei = (const int*)d_in[4];
    const float* gcn_w1  = (const float*)d_in[5];
    const float* gcn_b1  = (const float*)d_in[6];
    const float* gcn_w2  = (const float*)d_in[7];
    const float* gcn_b2  = (const float*)d_in[8];
    const float* gat_w1  = (const float*)d_in[9];
    const float* gat_as1 = (const float*)d_in[10];
    const float* gat_ad1 = (const float*)d_in[11];
    const float* gat_b1  = (const float*)d_in[12];
    const float* gat_w2  = (const float*)d_in[13];
    const float* gat_as2 = (const float*)d_in[14];
    const float* gat_ad2 = (const float*)d_in[15];
    const float* gat_b2  = (const float*)d_in[16];
    const float* cls_w1  = (const float*)d_in[17];
    const float* cls_b1  = (const float*)d_in[18];
    const float* cls_w2  = (const float*)d_in[19];
    const float* cls_b2  = (const float*)d_in[20];
    float* out = (float*)d_out;

    float* ws_f = (float*)d_ws;

    // ---- persistent tail ----
    float* T      = ws_f + 16777216;
    float* gsum   = T;                       // 262,144
    int*   gstart = (int*)(T + 262144);      // 4,096
    int*   gend   = (int*)(T + 266240);      // 4,096 (contiguous with gstart for one memset)
    float* psum   = T + 270336;              // 64
    int*   coarse = (int*)(T + 270400);      // 512
    int*   cstart = (int*)(T + 270912);      // 513
    int*   cursor = (int*)(T + 271425);      // 512

    // ---- mol-phase layout ----
    float*    h1M    = ws_f;                             // [0, 8388608)  (also molout overlay)
    float*    molout = ws_f;
    unsigned* bufM   = (unsigned*)ws_f;                  // EM (dead before h1M written)
    __half*   h2hM   = (__half*)(ws_f + 8388608);        // [8388608, 12582912)
    int*      molCOL = (int*)(ws_f + 12582912);          // EM+64 -> 13107264
    int*      molRP  = (int*)(ws_f + 13107264);          // NM -> 13238336, pad
    float*    dinvM  = ws_f + 13238352;                  // NM -> 13369424, pad
    float*    wM     = ws_f + 13369440;                  // EM+64 -> 13893792
    __half*   x8h    = (__half*)(ws_f + 13893792);       // NM*8 halves -> 14418080
    float*    aggM   = ws_f + 14418080;                  // NM*6 -> 15204512

    // ---- prot-phase layout (mol fully done first) ----
    float*    pP      = ws_f;                            // [0, 6400000)  (also protout overlay)
    float*    protout = ws_f;
    unsigned* bufP    = (unsigned*)ws_f;                 // EP (dead before pP written)
    __half*   h2hP    = (__half*)(ws_f + 6400000);       // [6400000, 9600000)
    int*      protCOL = (int*)(ws_f + 9600000);          // EP+64 -> 11200064
    int*      protRP  = (int*)(ws_f + 11200064);         // NP -> 11300064, pad
    float*    es      = ws_f + 11300080;                 // NP
    float*    ed_     = ws_f + 11400080;                 // NP
    float*    wP      = ws_f + 11500080;                 // EP+64 -> 13100144
    __half*   x32h    = (__half*)(ws_f + 13100144);      // NP*32 halves -> 14700144
    float*    aggP    = ws_f + 14700144;                 // NP*20 -> 16700144

    const int KM = 512;   // NM/256
    const int KPb = 391;  // cdiv(NP,256)

    // ================= mol branch =================
    hipMemsetAsync(coarse, 0, (size_t)KM * sizeof(int), stream);
    k_coarse_hist<2048><<<cdiv(EM,2048),256,0,stream>>>(mol_ei + EM, coarse, EM, KM);
    k_coarse_scan<<<1,512,0,stream>>>(coarse, cstart, cursor, KM, EM);
    k_part<2048,8><<<cdiv(EM,2048),256,0,stream>>>(mol_ei, cursor, bufM, EM, KM);
    k_fine<20,1><<<KM,256,0,stream>>>(bufM, cstart, molRP, molCOL, dinvM, NM, KM);
    k_wgcn<<<cdiv(EM,256),256,0,stream>>>(molCOL, dinvM, wM, EM);
    k_prep_mol<<<cdiv(NM,256),256,0,stream>>>(mol_x, x8h, NM);
    k_gather_x8<<<NM/4,256,0,stream>>>(molRP, molCOL, wM, x8h, dinvM, aggM);
    k_xw_small16<6,1><<<NM/16,256,0,stream>>>(aggM, gcn_w1, gcn_b1, h1M, NM);
    k_xw64h<0><<<NM/16,256,0,stream>>>(h1M, gcn_w2, nullptr, nullptr, h2hM, nullptr, nullptr, NM);
    k_gather64h<0,20><<<NM/4,256,0,stream>>>(molRP, molCOL, wM, h2hM, dinvM, nullptr, nullptr, gcn_b2, molout);
    hipMemsetAsync(gstart, 0, (size_t)(2 * NG) * sizeof(int), stream);
    k_segbounds<<<cdiv(NM,256),256,0,stream>>>(mol_bat, gstart, gend, NM);
    k_segpool<<<NG,64,0,stream>>>(gstart, gend, molout, gsum);

    // ================= prot branch =================
    hipMemsetAsync(coarse, 0, (size_t)KPb * sizeof(int), stream);
    k_coarse_hist<4096><<<cdiv(EP,4096),256,0,stream>>>(prot_ei + EP, coarse, EP, KPb);
    k_coarse_scan<<<1,512,0,stream>>>(coarse, cstart, cursor, KPb, EP);
    k_part<4096,16><<<cdiv(EP,4096),256,0,stream>>>(prot_ei, cursor, bufP, EP, KPb);
    k_fine<21,0><<<KPb,256,0,stream>>>(bufP, cstart, protRP, protCOL, nullptr, NP, KPb);
    k_prep_prot<<<cdiv(NP,256),256,0,stream>>>(prot_x, gat_w1, gat_as1, gat_ad1, x32h, es, ed_, NP);
    k_wcsr<21><<<cdiv(NP*16,256),256,0,stream>>>(protRP, protCOL, es, ed_, wP, NP);
    k_gather_x32<<<NP/4,256,0,stream>>>(protRP, protCOL, wP, x32h, es, ed_, aggP);
    k_xw_small16<20,1><<<NP/16,256,0,stream>>>(aggP, gat_w1, gat_b1, pP, NP);
    k_xw64h<1><<<NP/16,256,0,stream>>>(pP, gat_w2, gat_as2, gat_ad2, h2hP, es, ed_, NP);
    k_wcsr<21><<<cdiv(NP*16,256),256,0,stream>>>(protRP, protCOL, es, ed_, wP, NP);
    k_gather64h<1,21><<<NP/4,256,0,stream>>>(protRP, protCOL, wP, h2hP, nullptr, es, ed_, gat_b2, protout);
    hipMemsetAsync(psum, 0, 64 * sizeof(float), stream);
    k_pool_prot<<<1024,256,0,stream>>>(protout, psum, NP);

    // ================= classifier =================
    k_cls<<<NG/4,256,0,stream>>>(gsum, gstart, gend, psum, cls_w1, cls_b1, cls_w2, cls_b2, out);
}

// Round 11
// 462.272 us; speedup vs baseline: 1.5357x; 1.1528x over previous
//
#include <hip/hip_runtime.h>
#include <hip/hip_fp16.h>

#define NM 131072   // mol nodes
#define EM 524288   // mol edges
#define NG 4096     // graphs
#define DM 6        // mol in dim
#define NP 100000   // prot nodes
#define EP 1600000  // prot edges
#define DP 20       // prot in dim

static inline int cdiv(int a, int b){ return (a + b - 1) / b; }

__device__ __forceinline__ float leaky(float x){ return x > 0.f ? x : 0.2f * x; }

union H8 { float4 f4; __half2 h2[4]; };

// ================= bucketed CSR build (round-7, proven) =================
template<int CHUNK>
__global__ void k_coarse_hist(const int* __restrict__ dst, int* __restrict__ coarse,
                              int E, int K){
    __shared__ int lh[512];
    int t = threadIdx.x;
    for (int i = t; i < K; i += 256) lh[i] = 0;
    __syncthreads();
    int base = blockIdx.x * CHUNK;
    int end = min(base + CHUNK, E);
    for (int e = base + t; e < end; e += 256)
        atomicAdd(&lh[dst[e] >> 8], 1);
    __syncthreads();
    for (int i = t; i < K; i += 256)
        if (lh[i]) atomicAdd(&coarse[i], lh[i]);
}

__global__ void k_coarse_scan(const int* __restrict__ coarse, int* __restrict__ cstart,
                              int* __restrict__ cursor, int K, int E){
    int t = threadIdx.x, lane = t & 63, wid = t >> 6;
    int v0 = (t < K) ? coarse[t] : 0;
    int v = v0;
    #pragma unroll
    for (int off = 1; off < 64; off <<= 1) {
        int x = __shfl_up(v, off, 64);
        if (lane >= off) v += x;
    }
    __shared__ int ws[8];
    if (lane == 63) ws[wid] = v;
    __syncthreads();
    int add = 0;
    for (int w = 0; w < wid; w++) add += ws[w];
    int excl = v + add - v0;
    if (t < K) { cstart[t] = excl; cursor[t] = excl; }
    if (t == K - 1) cstart[K] = excl + v0;
}

template<int CHUNK, int EPT>
__global__ void k_part(const int* __restrict__ ei, int* __restrict__ cursor,
                       unsigned* __restrict__ buf, int E, int K){
    __shared__ int lh[512];
    __shared__ int lbase[512];
    int t = threadIdx.x;
    for (int i = t; i < K; i += 256) lh[i] = 0;
    __syncthreads();
    int base = blockIdx.x * CHUNK;
    int end = min(base + CHUNK, E);
    unsigned pay[EPT]; int bslot[EPT];
    int cnt = 0;
    for (int e = base + t; e < end; e += 256) {
        int u = ei[e], v = ei[E + e];
        int b = v >> 8;
        int ls = atomicAdd(&lh[b], 1);
        pay[cnt] = ((unsigned)(v & 255) << 24) | (unsigned)u;
        bslot[cnt] = (b << 13) | ls;
        cnt++;
    }
    __syncthreads();
    for (int i = t; i < K; i += 256)
        lbase[i] = lh[i] ? atomicAdd(&cursor[i], lh[i]) : 0;
    __syncthreads();
    for (int j = 0; j < cnt; j++) {
        int b = bslot[j] >> 13, ls = bslot[j] & 8191;
        buf[lbase[b] + ls] = pay[j];
    }
}

// fine: writes PACKED rp (start | deg<<OBITS) and optionally dinv directly
template<int OBITS, int DINV>
__global__ void k_fine(const unsigned* __restrict__ buf, const int* __restrict__ cstart,
                       int* __restrict__ rp, int* __restrict__ col,
                       float* __restrict__ dinv, int n, int K){
    int k = blockIdx.x, t = threadIdx.x;
    int start = cstart[k], end = cstart[k + 1];
    __shared__ int cnt[256];
    __shared__ int cur[256];
    cnt[t] = 0;
    __syncthreads();
    for (int p = start + t; p < end; p += 256)
        atomicAdd(&cnt[buf[p] >> 24], 1);
    __syncthreads();
    int v0 = cnt[t];
    int lane = t & 63, wid = t >> 6;
    int v = v0;
    #pragma unroll
    for (int off = 1; off < 64; off <<= 1) {
        int x = __shfl_up(v, off, 64);
        if (lane >= off) v += x;
    }
    __shared__ int ws[4];
    if (lane == 63) ws[wid] = v;
    __syncthreads();
    int add = 0;
    for (int w = 0; w < wid; w++) add += ws[w];
    int excl = v + add - v0;
    int ofs = start + excl;
    cur[t] = ofs;
    int idx = (k << 8) + t;
    if (idx < n) {
        rp[idx] = (int)((unsigned)ofs | ((unsigned)v0 << OBITS));
        if (DINV) dinv[idx] = rsqrtf((float)(v0 + 1));
    }
    __syncthreads();
    for (int p = start + t; p < end; p += 256) {
        unsigned pk = buf[p];
        int slot = atomicAdd(&cur[pk >> 24], 1);
        col[slot] = (int)(pk & 0xFFFFFFu);
    }
}

// ---------------- prep: mol x -> padded 8-half rows ----------------
__global__ void k_prep_mol(const float* __restrict__ x, __half* __restrict__ x8, int n){
    int i = blockIdx.x * 256 + threadIdx.x;
    if (i >= n) return;
    H8 r;
    #pragma unroll
    for (int k = 0; k < 3; k++)
        r.h2[k] = __floats2half2_rn(x[i*6 + 2*k], x[i*6 + 2*k + 1]);
    r.h2[3] = __floats2half2_rn(0.f, 0.f);
    *(float4*)&x8[(size_t)i * 8] = r.f4;
}

// ---------------- prep: prot x -> padded 32-half rows + es/ed dots ----------------
__global__ void k_prep_prot(const float* __restrict__ x, const float* __restrict__ W1,
                            const float* __restrict__ as_, const float* __restrict__ ad_,
                            __half* __restrict__ x32, float* __restrict__ es,
                            float* __restrict__ ed_, int n){
    __shared__ float vas[20], vds[20];
    int t = threadIdx.x;
    if (t < 20) {
        float s = 0.f;
        for (int j = 0; j < 64; j++) s += W1[t * 64 + j] * as_[j];
        vas[t] = s;
    } else if (t >= 32 && t < 52) {
        int k = t - 32;
        float s = 0.f;
        for (int j = 0; j < 64; j++) s += W1[k * 64 + j] * ad_[j];
        vds[k] = s;
    }
    __syncthreads();
    int i = blockIdx.x * 256 + t;
    if (i >= n) return;
    float xv[20];
    float s = 0.f, d = 0.f;
    #pragma unroll
    for (int k = 0; k < 20; k++) {
        xv[k] = x[i*20 + k];
        s += xv[k] * vas[k]; d += xv[k] * vds[k];
    }
    es[i] = s; ed_[i] = d;
    H8 r0, r1, r2, rz;
    #pragma unroll
    for (int k = 0; k < 4; k++) r0.h2[k] = __floats2half2_rn(xv[2*k],   xv[2*k+1]);
    #pragma unroll
    for (int k = 0; k < 4; k++) r1.h2[k] = __floats2half2_rn(xv[8+2*k], xv[9+2*k]);
    r2.h2[0] = __floats2half2_rn(xv[16], xv[17]);
    r2.h2[1] = __floats2half2_rn(xv[18], xv[19]);
    r2.h2[2] = __floats2half2_rn(0.f, 0.f);
    r2.h2[3] = __floats2half2_rn(0.f, 0.f);
    rz.h2[0] = rz.h2[1] = rz.h2[2] = rz.h2[3] = __floats2half2_rn(0.f, 0.f);
    *(float4*)&x32[(size_t)i * 32]      = r0.f4;
    *(float4*)&x32[(size_t)i * 32 + 8]  = r1.f4;
    *(float4*)&x32[(size_t)i * 32 + 16] = r2.f4;
    *(float4*)&x32[(size_t)i * 32 + 24] = rz.f4;
}

// ---------------- mol L1 gather: 8 lanes/node, 8 nodes/wave, inline dinv ----------------
__global__ void k_gather_x8(const int* __restrict__ rp, const int* __restrict__ col,
                            const __half* __restrict__ x8, const float* __restrict__ dinv,
                            float* __restrict__ agg){
    __shared__ float ost[192];
    int tid = threadIdx.x;
    int wv = tid >> 6, l = tid & 63, g = l >> 3, q = l & 7;
    int node = (blockIdx.x << 5) + (wv << 3) + g;
    unsigned pk = (unsigned)rp[node];
    int s0 = (int)(pk & 0xFFFFFu);
    int deg = (int)(pk >> 20);
    float dd = dinv[node];
    float acc[6] = {0.f,0.f,0.f,0.f,0.f,0.f};
    if (q == 0) {
        H8 r; r.f4 = *(const float4*)&x8[(size_t)node * 8];
        #pragma unroll
        for (int i = 0; i < 3; i++) {
            float2 f = __half22float2(r.h2[i]);
            acc[2*i] = dd * f.x; acc[2*i+1] = dd * f.y;
        }
    }
    for (int base = 0; base < deg; base += 8) {
        int s = base + q;
        int c = col[s0 + s];                 // +64 slack allocated
        int u = (s < deg) ? c : node;
        float wvv = (s < deg) ? dinv[u] : 0.f;
        H8 r; r.f4 = *(const float4*)&x8[(size_t)u * 8];
        #pragma unroll
        for (int i = 0; i < 3; i++) {
            float2 f = __half22float2(r.h2[i]);
            acc[2*i] += wvv * f.x; acc[2*i+1] += wvv * f.y;
        }
    }
    #pragma unroll
    for (int m = 1; m < 8; m <<= 1) {
        #pragma unroll
        for (int i = 0; i < 6; i++) acc[i] += __shfl_xor(acc[i], m, 8);
    }
    if (q == 0) {
        int slot = (wv << 3) + g;
        #pragma unroll
        for (int i = 0; i < 6; i++) ost[slot * 6 + i] = dd * acc[i];
    }
    __syncthreads();
    if (tid < 48)
        *(float4*)&agg[(size_t)blockIdx.x * 192 + (tid << 2)] = *(float4*)&ost[tid << 2];
}

// ---------------- prot L1 GAT gather: 16 slots x 4 lanes, inline exp weights ----------------
__global__ void k_gather_x32(const int* __restrict__ rp, const int* __restrict__ col,
                             const __half* __restrict__ x32, const float* __restrict__ es,
                             const float* __restrict__ ed_, float* __restrict__ agg){
    int tid = threadIdx.x;
    int node = (blockIdx.x << 2) + (tid >> 6);
    int l = tid & 63, g = l >> 2, q = l & 3;
    unsigned pk = (unsigned)rp[node];
    int s0 = (int)(pk & 0x1FFFFFu);
    int deg = (int)(pk >> 21);
    float edv = ed_[node];
    float selfw = __expf(leaky(es[node] + edv));
    float acc[8] = {0.f,0.f,0.f,0.f,0.f,0.f,0.f,0.f};
    float den = (l == 0) ? selfw : 0.f;
    if (g == 0 && q < 3) {
        H8 r; r.f4 = *(const float4*)&x32[(size_t)node * 32 + (q << 3)];
        #pragma unroll
        for (int i = 0; i < 4; i++) {
            float2 f = __half22float2(r.h2[i]);
            acc[2*i] = selfw * f.x; acc[2*i+1] = selfw * f.y;
        }
    }
    for (int base = 0; base < deg; base += 16) {
        int s = base + g;
        int c = col[s0 + s];
        int u = (s < deg) ? c : node;
        float wvv = (s < deg) ? __expf(leaky(es[u] + edv)) : 0.f;
        if (q < 3) {
            H8 r; r.f4 = *(const float4*)&x32[(size_t)u * 32 + (q << 3)];
            #pragma unroll
            for (int i = 0; i < 4; i++) {
                float2 f = __half22float2(r.h2[i]);
                acc[2*i] += wvv * f.x; acc[2*i+1] += wvv * f.y;
            }
        }
        if (q == 0) den += wvv;
    }
    #pragma unroll
    for (int m = 4; m <= 32; m <<= 1) {
        #pragma unroll
        for (int i = 0; i < 8; i++) acc[i] += __shfl_xor(acc[i], m, 64);
        den += __shfl_xor(den, m, 64);
    }
    den = __shfl(den, 0, 64);
    float inv = 1.f / den;
    if (g == 0) {
        if (q < 2) {
            float4 v0 = make_float4(acc[0]*inv, acc[1]*inv, acc[2]*inv, acc[3]*inv);
            float4 v1 = make_float4(acc[4]*inv, acc[5]*inv, acc[6]*inv, acc[7]*inv);
            *(float4*)&agg[(size_t)node * 20 + (q << 3)]     = v0;
            *(float4*)&agg[(size_t)node * 20 + (q << 3) + 4] = v1;
        } else if (q == 2) {
            float4 v0 = make_float4(acc[0]*inv, acc[1]*inv, acc[2]*inv, acc[3]*inv);
            *(float4*)&agg[(size_t)node * 20 + 16] = v0;
        }
    }
}

// ---------------- fused MLP: agg @ W1 + b1 -> relu -> @ W2 -> fp16 (+att dots) ----------------
// 16 nodes/block; requires n % 16 == 0 (NM, NP both satisfy)
template<int D, int ATT>
__global__ void k_mlp(const float* __restrict__ agg, const float* __restrict__ W1,
                      const float* __restrict__ b1, const float* __restrict__ W2,
                      const float* __restrict__ as_, const float* __restrict__ ad_,
                      __half* __restrict__ hout, float* __restrict__ es,
                      float* __restrict__ ed_){
    __shared__ float W1s[D * 64];
    __shared__ float W2s[64 * 64];
    __shared__ float A[16][D + 1];
    __shared__ float X1[16][68];
    int tid = threadIdx.x;
    for (int k = tid; k < D * 64; k += 256) W1s[k] = W1[k];
    for (int k = tid * 4; k < 4096; k += 1024)
        *(float4*)&W2s[k] = *(const float4*)&W2[k];
    int nd = tid >> 4, q = tid & 15;
    size_t node = (size_t)blockIdx.x * 16 + nd;
    for (int k = q; k < D; k += 16) A[nd][k] = agg[node * D + k];
    __syncthreads();
    float4 h1 = *(const float4*)&b1[q << 2];
    #pragma unroll
    for (int k = 0; k < D; k++) {
        float xk = A[nd][k];
        float4 w4 = *(const float4*)&W1s[(k << 6) + (q << 2)];
        h1.x += xk * w4.x; h1.y += xk * w4.y; h1.z += xk * w4.z; h1.w += xk * w4.w;
    }
    h1.x = fmaxf(h1.x, 0.f); h1.y = fmaxf(h1.y, 0.f);
    h1.z = fmaxf(h1.z, 0.f); h1.w = fmaxf(h1.w, 0.f);
    *(float4*)&X1[nd][q << 2] = h1;
    __syncthreads();
    float4 acc = {0.f, 0.f, 0.f, 0.f};
    #pragma unroll 8
    for (int k = 0; k < 64; k++) {
        float xk = X1[nd][k];
        float4 w4 = *(const float4*)&W2s[(k << 6) + (q << 2)];
        acc.x += xk * w4.x; acc.y += xk * w4.y; acc.z += xk * w4.z; acc.w += xk * w4.w;
    }
    union { __half2 h2[2]; float2 f2; } u;
    u.h2[0] = __floats2half2_rn(acc.x, acc.y);
    u.h2[1] = __floats2half2_rn(acc.z, acc.w);
    *(float2*)&hout[node * 64 + (q << 2)] = u.f2;
    if (ATT) {
        int f = q << 2;
        float xa = acc.x * as_[f] + acc.y * as_[f + 1] + acc.z * as_[f + 2] + acc.w * as_[f + 3];
        float ya = acc.x * ad_[f] + acc.y * ad_[f + 1] + acc.z * ad_[f + 2] + acc.w * ad_[f + 3];
        #pragma unroll
        for (int m = 1; m < 16; m <<= 1) {
            xa += __shfl_xor(xa, m, 16);
            ya += __shfl_xor(ya, m, 16);
        }
        if (q == 0) { es[node] = xa; ed_[node] = ya; }
    }
}

// ---------------- layer-2 gather over half rows: 8 slots x 8 lanes, inline weights ----------------
template<int GAT, int OBITS>
__global__ void k_gather64h(const int* __restrict__ rp, const int* __restrict__ col,
                            const __half* __restrict__ hh, const float* __restrict__ dinv,
                            const float* __restrict__ es, const float* __restrict__ ed_,
                            const float* __restrict__ b, float* __restrict__ out){
    int tid = threadIdx.x;
    int node = (blockIdx.x << 2) + (tid >> 6);
    int l = tid & 63, g = l >> 3, q = l & 7;
    unsigned pk = (unsigned)rp[node];
    int s0 = (int)(pk & ((1u << OBITS) - 1));
    int deg = (int)(pk >> OBITS);
    float edv = GAT ? ed_[node] : 0.f;
    float selfw = GAT ? __expf(leaky(es[node] + edv)) : dinv[node];
    float acc[8] = {0.f,0.f,0.f,0.f,0.f,0.f,0.f,0.f};
    float den = 0.f;
    if (g == 0) {
        H8 r; r.f4 = *(const float4*)&hh[(size_t)node * 64 + (q << 3)];
        #pragma unroll
        for (int i = 0; i < 4; i++) {
            float2 f = __half22float2(r.h2[i]);
            acc[2*i]     = selfw * f.x;
            acc[2*i + 1] = selfw * f.y;
        }
        den = selfw;
    }
    for (int base = 0; base < deg; base += 8) {
        int s = base + g;
        int c = col[s0 + s];
        int u = (s < deg) ? c : node;
        float wvv;
        if (GAT) wvv = (s < deg) ? __expf(leaky(es[u] + edv)) : 0.f;
        else     wvv = (s < deg) ? dinv[u] : 0.f;
        H8 r; r.f4 = *(const float4*)&hh[(size_t)u * 64 + (q << 3)];
        #pragma unroll
        for (int i = 0; i < 4; i++) {
            float2 f = __half22float2(r.h2[i]);
            acc[2*i]     += wvv * f.x;
            acc[2*i + 1] += wvv * f.y;
        }
        if (GAT && q == 0) den += wvv;
    }
    #pragma unroll
    for (int m = 8; m <= 32; m <<= 1) {
        #pragma unroll
        for (int i = 0; i < 8; i++) acc[i] += __shfl_xor(acc[i], m, 64);
        if (GAT) den += __shfl_xor(den, m, 64);
    }
    if (GAT) den = __shfl(den, 0, 64);
    if (g == 0) {
        float sc = GAT ? (1.f / den) : selfw;
        int f = q << 3;
        float4 v0, v1;
        v0.x = acc[0]*sc + b[f];     v0.y = acc[1]*sc + b[f+1];
        v0.z = acc[2]*sc + b[f+2];   v0.w = acc[3]*sc + b[f+3];
        v1.x = acc[4]*sc + b[f+4];   v1.y = acc[5]*sc + b[f+5];
        v1.z = acc[6]*sc + b[f+6];   v1.w = acc[7]*sc + b[f+7];
        *(float4*)&out[(size_t)node * 64 + f]     = v0;
        *(float4*)&out[(size_t)node * 64 + f + 4] = v1;
    }
}

// ---------------- mol pooling: boundary-based segments (batch sorted) ----------------
__global__ void k_segbounds(const int* __restrict__ batch, int* __restrict__ gstart,
                            int* __restrict__ gend, int n){
    int i = blockIdx.x * 256 + threadIdx.x;
    if (i >= n) return;
    int g = batch[i];
    if (i == 0 || batch[i - 1] != g) gstart[g] = i;
    if (i == n - 1 || batch[i + 1] != g) gend[g] = i + 1;
}
__global__ void k_segpool(const int* __restrict__ gstart, const int* __restrict__ gend,
                          const float* __restrict__ x, float* __restrict__ gsum){
    int gph = blockIdx.x, t = threadIdx.x;
    int rg = t >> 4, q = t & 15;
    int s = gstart[gph], c = gend[gph] - gstart[gph];
    float4 a = {0.f, 0.f, 0.f, 0.f};
    for (int i = rg; i < c; i += 4) {
        float4 v = *(const float4*)&x[(size_t)(s + i) * 64 + (q << 2)];
        a.x += v.x; a.y += v.y; a.z += v.z; a.w += v.w;
    }
    #pragma unroll
    for (int m = 16; m <= 32; m <<= 1) {
        a.x += __shfl_xor(a.x, m, 64);
        a.y += __shfl_xor(a.y, m, 64);
        a.z += __shfl_xor(a.z, m, 64);
        a.w += __shfl_xor(a.w, m, 64);
    }
    if (rg == 0) *(float4*)&gsum[gph * 64 + (q << 2)] = a;
}

// ---------------- prot pooling ----------------
__global__ void k_pool_prot(const float* __restrict__ x, float* __restrict__ psum, int n){
    __shared__ float red[4][64];
    int t = threadIdx.x, lane = t & 63, wv = t >> 6;
    const float4* x4 = (const float4*)x;
    int total = n * 16;
    float4 a = {0.f, 0.f, 0.f, 0.f};
    for (int i = blockIdx.x * 256 + t; i < total; i += gridDim.x * 256) {
        float4 v = x4[i];
        a.x += v.x; a.y += v.y; a.z += v.z; a.w += v.w;
    }
    #pragma unroll
    for (int m = 16; m <= 32; m <<= 1) {
        a.x += __shfl_xor(a.x, m, 64);
        a.y += __shfl_xor(a.y, m, 64);
        a.z += __shfl_xor(a.z, m, 64);
        a.w += __shfl_xor(a.w, m, 64);
    }
    if (lane < 16) *(float4*)&red[wv][lane << 2] = a;
    __syncthreads();
    if (t < 64) {
        float s = red[0][t] + red[1][t] + red[2][t] + red[3][t];
        atomicAdd(&psum[t], s);
    }
}

// ---------------- fused classifier ----------------
__global__ void k_cls(const float* __restrict__ gsum, const int* __restrict__ gstart,
                      const int* __restrict__ gend, const float* __restrict__ psum,
                      const float* __restrict__ W1, const float* __restrict__ b1,
                      const float* __restrict__ w2, const float* __restrict__ b2,
                      float* __restrict__ out){
    __shared__ float W1s[128 * 64];
    int tid = threadIdx.x;
    for (int k = tid; k < 128 * 64; k += 256) W1s[k] = W1[k];
    __syncthreads();
    int g = blockIdx.x * 4 + (tid >> 6);
    int j = tid & 63;
    float cntf = (float)(gend[g] - gstart[g]);
    float inv = 1.0f / fmaxf(cntf, 1.0f);
    const float invp = 1.0f / (float)NP;
    float acc = b1[j];
    #pragma unroll 8
    for (int k = 0; k < 64; k++) acc += (gsum[g * 64 + k] * inv) * W1s[k * 64 + j];
    #pragma unroll 8
    for (int k = 0; k < 64; k++) acc += (psum[k] * invp) * W1s[(64 + k) * 64 + j];
    float v = fmaxf(acc, 0.f) * w2[j];
    #pragma unroll
    for (int off = 32; off > 0; off >>= 1) v += __shfl_down(v, off, 64);
    if (j == 0) out[g] = 1.0f / (1.0f + expf(-(v + b2[0])));
}

extern "C" void kernel_launch(void* const* d_in, const int* in_sizes, int n_in,
                              void* d_out, int out_size, void* d_ws, size_t ws_size,
                              hipStream_t stream) {
    const float* mol_x   = (const float*)d_in[0];
    const int*   mol_ei  = (const int*)d_in[1];
    const int*   mol_bat = (const int*)d_in[2];
    const float* prot_x  = (const float*)d_in[3];
    const int*   prot_ei = (const int*)d_in[4];
    const float* gcn_w1  = (const float*)d_in[5];
    const float* gcn_b1  = (const float*)d_in[6];
    const float* gcn_w2  = (const float*)d_in[7];
    const float* gcn_b2  = (const float*)d_in[8];
    const float* gat_w1  = (const float*)d_in[9];
    const float* gat_as1 = (const float*)d_in[10];
    const float* gat_ad1 = (const float*)d_in[11];
    const float* gat_b1  = (const float*)d_in[12];
    const float* gat_w2  = (const float*)d_in[13];
    const float* gat_as2 = (const float*)d_in[14];
    const float* gat_ad2 = (const float*)d_in[15];
    const float* gat_b2  = (const float*)d_in[16];
    const float* cls_w1  = (const float*)d_in[17];
    const float* cls_b1  = (const float*)d_in[18];
    const float* cls_w2  = (const float*)d_in[19];
    const float* cls_b2  = (const float*)d_in[20];
    float* out = (float*)d_out;

    float* ws_f = (float*)d_ws;

    // ---- persistent tail ----
    float* T      = ws_f + 16777216;
    float* gsum   = T;                       // 262,144
    int*   gstart = (int*)(T + 262144);      // 4,096
    int*   gend   = (int*)(T + 266240);      // 4,096
    float* psum   = T + 270336;              // 64
    int*   coarse = (int*)(T + 270400);      // 512
    int*   cstart = (int*)(T + 270912);      // 513
    int*   cursor = (int*)(T + 271425);      // 512

    // ---- mol-phase layout ----
    float*    molout = ws_f;                             // [0, 8388608)
    unsigned* bufM   = (unsigned*)ws_f;                  // EM (dead before molout)
    __half*   h2hM   = (__half*)(ws_f + 8388608);        // [8388608, 12582912)
    int*      molCOL = (int*)(ws_f + 12582912);          // EM+64 -> 13107264
    int*      molRP  = (int*)(ws_f + 13107264);          // NM -> 13238336, pad
    float*    dinvM  = ws_f + 13238352;                  // NM -> 13369424, pad
    __half*   x8h    = (__half*)(ws_f + 13369440);       // NM*8 halves -> 13893728, pad
    float*    aggM   = ws_f + 13893792;                  // NM*6 -> 14680224

    // ---- prot-phase layout (mol fully done first) ----
    float*    protout = ws_f;                            // [0, 6400000)
    unsigned* bufP    = (unsigned*)ws_f;                 // EP (dead before protout)
    __half*   h2hP    = (__half*)(ws_f + 6400000);       // [6400000, 9600000)
    int*      protCOL = (int*)(ws_f + 9600000);          // EP+64 -> 11200064
    int*      protRP  = (int*)(ws_f + 11200064);         // NP -> 11300064, pad
    float*    es      = ws_f + 11300080;                 // NP
    float*    ed_     = ws_f + 11400080;                 // NP
    __half*   x32h    = (__half*)(ws_f + 11500080);      // NP*32 halves -> 13100080, pad
    float*    aggP    = ws_f + 13100144;                 // NP*20 -> 15100144

    const int KM = 512;   // NM/256
    const int KPb = 391;  // cdiv(NP,256)

    // ================= mol branch =================
    hipMemsetAsync(coarse, 0, (size_t)KM * sizeof(int), stream);
    k_coarse_hist<2048><<<cdiv(EM,2048),256,0,stream>>>(mol_ei + EM, coarse, EM, KM);
    k_coarse_scan<<<1,512,0,stream>>>(coarse, cstart, cursor, KM, EM);
    k_part<2048,8><<<cdiv(EM,2048),256,0,stream>>>(mol_ei, cursor, bufM, EM, KM);
    k_fine<20,1><<<KM,256,0,stream>>>(bufM, cstart, molRP, molCOL, dinvM, NM, KM);
    k_prep_mol<<<cdiv(NM,256),256,0,stream>>>(mol_x, x8h, NM);
    k_gather_x8<<<NM/32,256,0,stream>>>(molRP, molCOL, x8h, dinvM, aggM);
    k_mlp<6,0><<<NM/16,256,0,stream>>>(aggM, gcn_w1, gcn_b1, gcn_w2, nullptr, nullptr, h2hM, nullptr, nullptr);
    k_gather64h<0,20><<<NM/4,256,0,stream>>>(molRP, molCOL, h2hM, dinvM, nullptr, nullptr, gcn_b2, molout);
    hipMemsetAsync(gstart, 0, (size_t)(2 * NG) * sizeof(int), stream);
    k_segbounds<<<cdiv(NM,256),256,0,stream>>>(mol_bat, gstart, gend, NM);
    k_segpool<<<NG,64,0,stream>>>(gstart, gend, molout, gsum);

    // ================= prot branch =================
    hipMemsetAsync(coarse, 0, (size_t)KPb * sizeof(int), stream);
    k_coarse_hist<4096><<<cdiv(EP,4096),256,0,stream>>>(prot_ei + EP, coarse, EP, KPb);
    k_coarse_scan<<<1,512,0,stream>>>(coarse, cstart, cursor, KPb, EP);
    k_part<4096,16><<<cdiv(EP,4096),256,0,stream>>>(prot_ei, cursor, bufP, EP, KPb);
    k_fine<21,0><<<KPb,256,0,stream>>>(bufP, cstart, protRP, protCOL, nullptr, NP, KPb);
    k_prep_prot<<<cdiv(NP,256),256,0,stream>>>(prot_x, gat_w1, gat_as1, gat_ad1, x32h, es, ed_, NP);
    k_gather_x32<<<NP/4,256,0,stream>>>(protRP, protCOL, x32h, es, ed_, aggP);
    k_mlp<20,1><<<NP/16,256,0,stream>>>(aggP, gat_w1, gat_b1, gat_w2, gat_as2, gat_ad2, h2hP, es, ed_);
    k_gather64h<1,21><<<NP/4,256,0,stream>>>(protRP, protCOL, h2hP, nullptr, es, ed_, gat_b2, protout);
    hipMemsetAsync(psum, 0, 64 * sizeof(float), stream);
    k_pool_prot<<<1024,256,0,stream>>>(protout, psum, NP);

    // ================= classifier =================
    k_cls<<<NG/4,256,0,stream>>>(gsum, gstart, gend, psum, cls_w1, cls_b1, cls_w2, cls_b2, out);
}